// Round 13
// baseline (421.957 us; speedup 1.0000x reference)
//
#include <hip/hip_runtime.h>
#include <cstddef>
#include <cstdint>

#define BATCH 32

// All intermediates are NODE-MAJOR: X[n][b][f]  (addr = (n*32 + b)*F + f).
// Workspace (floats):
//   Xt : 1,572,864   (transposed input, [16384][32][3])
//   T  : 20,971,520  (T1..T5; max slice = layer1: 4096*32*32 = 4,194,304)
//   X1 : 4,194,304   ([4096][32][32])
//   X2 : 1,048,576   ([1024][32][32])
//   X3 : 262,144     ([256][32][32])
//   X4 : 131,072     ([32][4096] batch-major for encoder)
//   P  : 65,536      (encoder split-K partials)

__device__ __forceinline__ void fma4(float4& a, float s, const float4& w) {
  a.x += s * w.x; a.y += s * w.y; a.z += s * w.z; a.w += s * w.w;
}
__device__ __forceinline__ float4 relu4(const float4& a) {
  return make_float4(fmaxf(a.x, 0.f), fmaxf(a.y, 0.f), fmaxf(a.z, 0.f), fmaxf(a.w, 0.f));
}

// ---------------- transpose x[b][n][3] -> Xt[n][b][3] ----------------
__global__ void __launch_bounds__(256) transpose_x(
    const float* __restrict__ x, float* __restrict__ xt)
{
  int t = blockIdx.x * 256 + threadIdx.x;     // n*96 + b*3 + f
  int n = t / 96;
  int r = t % 96;
  int b = r / 3;
  int f = r - b * 3;
  xt[t] = x[((size_t)b * 16384 + n) * 3 + f];
}

// ---------------- LDS-resident Chebyshev recurrence, layer 0 (FS=1) ----------------
// Block = (b, f) with f in {0,1,2}: 96 blocks x 1024 threads, cur[16384] = 64 KB.
// Structure mirrors the proven R10 v3 recur (per-step LDS gather, write inside
// the step, prev re-read from own LDS slot after the barrier). Replaces the
// 5-dispatch global chain (~85 us: 5 x (6 MB slice write + ~36 MB gather
// re-reads that miss the 4 MB/XCD L2)).
template<int N, int THREADS, int MINW>
__global__ void __launch_bounds__(THREADS, MINW) cheb_recur_f3(
    const float* __restrict__ X,    // node-major [N][32][3]
    const int* __restrict__ ec,     // [N][6]
    float* __restrict__ T)          // 5 slices, node-major [N][32][3]
{
  constexpr int NPT = N / THREADS;             // 16
  __shared__ float cur[N];
  const float cI = -1.0f / 6.0f;
  const float cS = -1.0f / 3.0f;
  const int b = blockIdx.x & 31;
  const int f = blockIdx.x >> 5;               // 0..2
  constexpr size_t SL = (size_t)N * 32 * 3;    // slice stride (floats)
  float prevv[NPT];                            // T_{k-2} at owned nodes
  // load T0 slab
#pragma unroll
  for (int i = 0; i < NPT; ++i) {
    int n = threadIdx.x + i * THREADS;
    cur[n] = X[((size_t)n * 32 + b) * 3 + f];
  }
  __syncthreads();
#pragma unroll 1
  for (int k = 1; k <= 5; ++k) {
    float newv[NPT];
    float* Tk = T + (size_t)(k - 1) * SL;
#pragma unroll
    for (int i = 0; i < NPT; ++i) {
      int n = threadIdx.x + i * THREADS;
      const int* e = ec + n * 6;
      float s = 0.f;
#pragma unroll
      for (int d = 0; d < 6; ++d) s += cur[e[d]];
      float v = (k == 1) ? (cI * s) : (cS * s - prevv[i]);
      newv[i] = v;
      Tk[((size_t)n * 32 + b) * 3 + f] = v;
    }
    __syncthreads();   // all gathers of T_{k-1} complete
#pragma unroll
    for (int i = 0; i < NPT; ++i) {
      int n = threadIdx.x + i * THREADS;
      prevv[i] = cur[n];                       // own slot still = T_{k-1}
      cur[n] = newv[i];                        // T_k -> cur
    }
    __syncthreads();
  }
}

// ---------------- LDS-resident Chebyshev recurrence v3 (layers 1-3, FS=2) ----------------
// R10's exact version: best measured (67 us at layer 1).
template<int N, int F, int THREADS, int MINW>
__global__ void __launch_bounds__(THREADS, MINW) cheb_recur_reg(
    const float* __restrict__ X,    // node-major [N][32][F]
    const int* __restrict__ ec,     // [N][6]
    float* __restrict__ T)          // 5 slices, node-major
{
  constexpr int FS = 2;
  constexpr int NPT = N / THREADS;             // nodes per thread
  __shared__ float cur[N * FS];
  const float cI = -1.0f / 6.0f;
  const float cS = -1.0f / 3.0f;
  const int b = blockIdx.x & 31;
  const int fbase = (blockIdx.x >> 5) * FS;
  constexpr size_t SL = (size_t)N * 32 * F;    // slice stride (floats)
  float prevv[NPT][FS];                        // T_{k-2} at owned nodes
  // load T0 slab
#pragma unroll
  for (int i = 0; i < NPT; ++i) {
    int n = threadIdx.x + i * THREADS;
    float2 v = *(const float2*)(X + ((size_t)n * 32 + b) * F + fbase);
    cur[n * FS + 0] = v.x;
    cur[n * FS + 1] = v.y;
  }
  __syncthreads();
#pragma unroll 1
  for (int k = 1; k <= 5; ++k) {
    float newv[NPT][FS];
    float* Tk = T + (size_t)(k - 1) * SL;
#pragma unroll
    for (int i = 0; i < NPT; ++i) {
      int n = threadIdx.x + i * THREADS;
      const int* e = ec + n * 6;
      float s0 = 0.f, s1 = 0.f;
#pragma unroll
      for (int d = 0; d < 6; ++d) {
        int c = e[d];
        s0 += cur[c * FS + 0];
        s1 += cur[c * FS + 1];
      }
      float v0, v1;
      if (k == 1) { v0 = cI * s0; v1 = cI * s1; }
      else        { v0 = cS * s0 - prevv[i][0]; v1 = cS * s1 - prevv[i][1]; }
      newv[i][0] = v0; newv[i][1] = v1;
      *(float2*)(Tk + ((size_t)n * 32 + b) * F + fbase) = make_float2(v0, v1);
    }
    __syncthreads();   // all gathers of T_{k-1} complete
#pragma unroll
    for (int i = 0; i < NPT; ++i) {
      int n = threadIdx.x + i * THREADS;
      prevv[i][0] = cur[n * FS + 0];           // own slot still = T_{k-1}
      prevv[i][1] = cur[n * FS + 1];
      cur[n * FS + 0] = newv[i][0];            // T_k -> cur
      cur[n * FS + 1] = newv[i][1];
    }
    __syncthreads();
  }
}

// ---------------- fused pool(relu(conv)), FIN=3, materialized T1..T5 ----------------
template<int N, int M, int FOUT, bool OUT_BM>
__global__ void __launch_bounds__(256) pool_conv_f3(
    const float* __restrict__ X, const float* __restrict__ T,
    const float* __restrict__ W, const float* __restrict__ bias,
    const int* __restrict__ pc, const float* __restrict__ pv,
    float* __restrict__ out)
{
  constexpr int F4 = FOUT / 4;
  constexpr size_t SL = (size_t)N * BATCH * 3;   // slice stride (floats)
  __shared__ float Ws[6 * 3 * FOUT];
  for (int i = threadIdx.x; i < 6 * 3 * FOUT; i += 256) Ws[i] = W[i];
  __syncthreads();
  const float4* Ws4 = (const float4*)Ws;
  int t = blockIdx.x * 256 + threadIdx.x;     // exact grid: M*32*F4
  int fo4 = t % F4;
  int b   = (t / F4) % BATCH;
  int m   = t / (F4 * BATCH);
  int c0 = pc[m * 3 + 0], c1 = pc[m * 3 + 1], c2 = pc[m * 3 + 2];
  float v0 = pv[m * 3 + 0], v1 = pv[m * 3 + 1], v2 = pv[m * 3 + 2];
  float4 bi = ((const float4*)bias)[fo4];
  float4 a0 = bi, a1 = bi, a2 = bi;
#pragma unroll
  for (int k = 0; k < 6; ++k) {
    const float* base = (k == 0) ? X : (T + (size_t)(k - 1) * SL);
    const float* r0 = base + ((size_t)c0 * BATCH + b) * 3;
    const float* r1 = base + ((size_t)c1 * BATCH + b) * 3;
    const float* r2 = base + ((size_t)c2 * BATCH + b) * 3;
#pragma unroll
    for (int f = 0; f < 3; ++f) {
      float4 w = Ws4[(k * 3 + f) * F4 + fo4];
      fma4(a0, r0[f], w);
      fma4(a1, r1[f], w);
      fma4(a2, r2[f], w);
    }
  }
  a0 = relu4(a0); a1 = relu4(a1); a2 = relu4(a2);
  float4 acc;
  acc.x = v0*a0.x + v1*a1.x + v2*a2.x;
  acc.y = v0*a0.y + v1*a1.y + v2*a2.y;
  acc.z = v0*a0.z + v1*a1.z + v2*a2.z;
  acc.w = v0*a0.w + v1*a1.w + v2*a2.w;
  size_t oi = OUT_BM ? (((size_t)b * M + m) * F4 + fo4) : (((size_t)m * BATCH + b) * F4 + fo4);
  ((float4*)out)[oi] = acc;
}

// ---------------- fused pool(relu(conv)), FIN=32, node-major T ----------------
template<int N, int M, int FOUT, bool OUT_BM>
__global__ void __launch_bounds__(256) pool_conv_v32(
    const float* __restrict__ X, const float* __restrict__ T,
    const float* __restrict__ W, const float* __restrict__ bias,
    const int* __restrict__ pc, const float* __restrict__ pv,
    float* __restrict__ out)
{
  constexpr int FIN = 32;
  constexpr int F4 = FOUT / 4;
  constexpr size_t SL4 = (size_t)N * BATCH * FIN / 4;   // slice stride (float4)
  __shared__ float Ws[6 * FIN * FOUT];                  // 24 KB or 48 KB
  for (int i = threadIdx.x; i < 6 * FIN * FOUT; i += 256) Ws[i] = W[i];
  __syncthreads();
  const float4* Ws4 = (const float4*)Ws;
  const float4* X4p = (const float4*)X;
  const float4* T4s = (const float4*)T;
  int t = blockIdx.x * 256 + threadIdx.x;     // exact grid: M*32*F4
  int fo4 = t % F4;
  int b   = (t / F4) % BATCH;
  int m   = t / (F4 * BATCH);
  int c0 = pc[m * 3 + 0], c1 = pc[m * 3 + 1], c2 = pc[m * 3 + 2];
  float v0 = pv[m * 3 + 0], v1 = pv[m * 3 + 1], v2 = pv[m * 3 + 2];
  float4 bi = ((const float4*)bias)[fo4];
  float4 a0 = bi, a1 = bi, a2 = bi;
#pragma unroll 1
  for (int k = 0; k < 6; ++k) {
    const float4* base = (k == 0) ? X4p : (T4s + (size_t)(k - 1) * SL4);
    const float4* r0 = base + ((size_t)c0 * BATCH + b) * 8;
    const float4* r1 = base + ((size_t)c1 * BATCH + b) * 8;
    const float4* r2 = base + ((size_t)c2 * BATCH + b) * 8;
#pragma unroll
    for (int fi = 0; fi < 8; ++fi) {
      float4 t0 = r0[fi], t1 = r1[fi], t2 = r2[fi];
#pragma unroll
      for (int ff = 0; ff < 4; ++ff) {
        float4 w = Ws4[((k * 32) + fi * 4 + ff) * F4 + fo4];
        fma4(a0, ((const float*)&t0)[ff], w);
        fma4(a1, ((const float*)&t1)[ff], w);
        fma4(a2, ((const float*)&t2)[ff], w);
      }
    }
  }
  a0 = relu4(a0); a1 = relu4(a1); a2 = relu4(a2);
  float4 acc;
  acc.x = v0*a0.x + v1*a1.x + v2*a2.x;
  acc.y = v0*a0.y + v1*a1.y + v2*a2.y;
  acc.z = v0*a0.z + v1*a1.z + v2*a2.z;
  acc.w = v0*a0.w + v1*a1.w + v2*a2.w;
  size_t oi = OUT_BM ? (((size_t)b * M + m) * F4 + fo4) : (((size_t)m * BATCH + b) * F4 + fo4);
  ((float4*)out)[oi] = acc;
}

// ---------------- encoder split-K partial ----------------
__global__ void __launch_bounds__(256) encoder_partial(
    const float* __restrict__ Xf, const float* __restrict__ encW,
    float* __restrict__ partial)
{
  int b  = blockIdx.x;        // 0..31
  int ks = blockIdx.y;        // 0..15
  int fo = threadIdx.x & 127;
  int half = threadIdx.x >> 7;
  const float* xr = Xf + b * 4096 + ks * 256 + half * 128;
  const float* w  = encW + (size_t)(ks * 256 + half * 128) * 128;
  float acc = 0.f;
#pragma unroll 8
  for (int i = 0; i < 128; ++i) acc += xr[i] * w[(size_t)i * 128 + fo];
  __shared__ float part[256];
  part[threadIdx.x] = acc;
  __syncthreads();
  if (half == 0) partial[(size_t)(b * 16 + ks) * 128 + fo] = part[fo] + part[128 + fo];
}

// ---------------- fused encoder-reduce + relu + classifier ----------------
__global__ void __launch_bounds__(128) encoder_reduce_cls(
    const float* __restrict__ partial, const float* __restrict__ encB,
    const float* __restrict__ clsW, const float* __restrict__ clsB,
    float* __restrict__ out)
{
  int b = blockIdx.x;           // 0..31
  int fo = threadIdx.x;         // 0..127
  float acc = encB[fo];
#pragma unroll
  for (int ks = 0; ks < 16; ++ks) acc += partial[(size_t)(b * 16 + ks) * 128 + fo];
  __shared__ float Hs[128];
  Hs[fo] = fmaxf(acc, 0.f);
  __syncthreads();
  if (fo < 10) {
    float s = clsB[fo];
#pragma unroll 4
    for (int f = 0; f < 128; ++f) s += Hs[f] * clsW[f * 10 + fo];
    out[b * 10 + fo] = s;
  }
}

extern "C" void kernel_launch(void* const* d_in, const int* in_sizes, int n_in,
                              void* d_out, int out_size, void* d_ws, size_t ws_size,
                              hipStream_t stream)
{
  const float* x   = (const float*)d_in[0];
  const int* ec0 = (const int*)d_in[2];
  const int* ec1 = (const int*)d_in[4];
  const int* ec2 = (const int*)d_in[6];
  const int* ec3 = (const int*)d_in[8];
  const int* pc0 = (const int*)d_in[10]; const float* pv0 = (const float*)d_in[11];
  const int* pc1 = (const int*)d_in[13]; const float* pv1 = (const float*)d_in[14];
  const int* pc2 = (const int*)d_in[16]; const float* pv2 = (const float*)d_in[17];
  const int* pc3 = (const int*)d_in[19]; const float* pv3 = (const float*)d_in[20];
  const float* W0 = (const float*)d_in[21]; const float* b0 = (const float*)d_in[22];
  const float* W1 = (const float*)d_in[23]; const float* b1 = (const float*)d_in[24];
  const float* W2 = (const float*)d_in[25]; const float* b2 = (const float*)d_in[26];
  const float* W3 = (const float*)d_in[27]; const float* b3 = (const float*)d_in[28];
  const float* encW = (const float*)d_in[29]; const float* encB = (const float*)d_in[30];
  const float* clsW = (const float*)d_in[31]; const float* clsB = (const float*)d_in[32];
  float* out = (float*)d_out;

  float* ws = (float*)d_ws;
  float* Xt = ws;                       // 1,572,864
  float* T  = Xt + 1572864;             // 20,971,520 (T1..T5, layer-1 sized)
  float* X1 = T  + 20971520;            // 4,194,304
  float* X2 = X1 + 4194304;             // 1,048,576
  float* X3 = X2 + 1048576;             // 262,144
  float* X4 = X3 + 262144;              // 131,072  ([32][4096])
  float* P  = X4 + 131072;              // 65,536

  dim3 blk(256);

  transpose_x<<<dim3(6144), blk, 0, stream>>>(x, Xt);

  // ================= layer 0: N=16384, F=3, M=4096 =================
  // LDS-resident recurrence: 96 blocks (32 b x 3 f) x 1024 thr, 64 KB LDS.
  // Replaces the 5-dispatch global chain (~85 us).
  {
    cheb_recur_f3<16384, 1024, 2><<<dim3(96), dim3(1024), 0, stream>>>(Xt, ec0, T);
    pool_conv_f3<16384, 4096, 32, false><<<dim3(4096), blk, 0, stream>>>(
        Xt, T, W0, b0, pc0, pv0, X1);
  }
  // ================= layer 1: N=4096, F=32, M=1024 =================
  // R10's exact config: 512 blocks x 512 thr, 32 KB LDS, MINW=4.
  {
    cheb_recur_reg<4096, 32, 512, 4><<<dim3(512), dim3(512), 0, stream>>>(X1, ec1, T);
    pool_conv_v32<4096, 1024, 32, false><<<dim3(1024), blk, 0, stream>>>(
        X1, T, W1, b1, pc1, pv1, X2);
  }
  // ================= layer 2: N=1024, F=32, M=256 =================
  {
    cheb_recur_reg<1024, 32, 256, 4><<<dim3(512), blk, 0, stream>>>(X2, ec2, T);
    pool_conv_v32<1024, 256, 32, false><<<dim3(256), blk, 0, stream>>>(
        X2, T, W2, b2, pc2, pv2, X3);
  }
  // ================= layer 3: N=256, F=32, M=64, FOUT=64, batch-major out =================
  {
    cheb_recur_reg<256, 32, 256, 4><<<dim3(512), blk, 0, stream>>>(X3, ec3, T);
    pool_conv_v32<256, 64, 64, true><<<dim3(128), blk, 0, stream>>>(
        X3, T, W3, b3, pc3, pv3, X4);
  }
  // ================= head =================
  encoder_partial<<<dim3(32, 16), blk, 0, stream>>>(X4, encW, P);
  encoder_reduce_cls<<<dim3(32), dim3(128), 0, stream>>>(P, encB, clsW, clsB, out);
}

// Round 14
// 319.187 us; speedup vs baseline: 1.3220x; 1.3220x over previous
//
#include <hip/hip_runtime.h>
#include <hip/hip_fp16.h>
#include <cstddef>
#include <cstdint>

#define BATCH 32

// T and the transposed input are stored FP16 (compute fp32). Layouts:
//   Xh : [16384][32][4] halves (pad=0)        = 1,048,576 floats region
//   Th : T1..T5; layer0 slices [n][32][4]h, layers1-3 [n][32][32]h
//        region = 10,485,760 floats (20,971,520 halves)
//   X1 : 4,194,304 fp32   X2 : 1,048,576   X3 : 262,144
//   X4 : 131,072 ([32][4096] fp32, batch-major)   P : 65,536

struct alignas(8) half4 { __half2 lo, hi; };

__device__ __forceinline__ void h4f(const half4 h, float f[4]) {
  float2 a = __half22float2(h.lo);
  float2 c = __half22float2(h.hi);
  f[0] = a.x; f[1] = a.y; f[2] = c.x; f[3] = c.y;
}
__device__ __forceinline__ void fma4(float4& a, float s, const float4& w) {
  a.x += s * w.x; a.y += s * w.y; a.z += s * w.z; a.w += s * w.w;
}
__device__ __forceinline__ float4 relu4(const float4& a) {
  return make_float4(fmaxf(a.x, 0.f), fmaxf(a.y, 0.f), fmaxf(a.z, 0.f), fmaxf(a.w, 0.f));
}

// ---------------- transpose x[b][n][3] -> Xh[n][32][4] fp16 (pad=0) ----------------
__global__ void __launch_bounds__(256) transpose_h(
    const float* __restrict__ x, half4* __restrict__ xh)
{
  int t = blockIdx.x * 256 + threadIdx.x;   // n*32 + b
  int n = t >> 5;
  int b = t & 31;
  const float* src = x + ((size_t)b * 16384 + n) * 3;
  half4 h;
  h.lo = __floats2half2_rn(src[0], src[1]);
  h.hi = __floats2half2_rn(src[2], 0.f);
  xh[t] = h;
}

// ---------------- fp16 Cheb step, layer 0 ----------------
// One thread per (n,b) cell. Slice = 4 MB -> fits one XCD's L2; gathers hit L2.
template<int N>
__global__ void __launch_bounds__(256) cheb_step_h(
    const half4* __restrict__ Tin, const half4* __restrict__ Tpp,
    const int* __restrict__ ec, half4* __restrict__ Tout,
    float coef, float beta)
{
  int idx = blockIdx.x * 256 + threadIdx.x;   // n*32 + b, exact grid
  int n = idx >> 5;
  int b = idx & 31;
  const int* e = ec + n * 6;
  float s0 = 0.f, s1 = 0.f, s2 = 0.f;
#pragma unroll
  for (int d = 0; d < 6; ++d) {
    half4 v = Tin[(e[d] << 5) | b];
    float2 a = __half22float2(v.lo);
    float2 c = __half22float2(v.hi);
    s0 += a.x; s1 += a.y; s2 += c.x;
  }
  half4 p = Tpp[idx];
  float2 pa = __half22float2(p.lo);
  float2 pc = __half22float2(p.hi);
  half4 o;
  o.lo = __floats2half2_rn(coef * s0 + beta * pa.x, coef * s1 + beta * pa.y);
  o.hi = __floats2half2_rn(coef * s2 + beta * pc.x, 0.f);
  Tout[idx] = o;
}

// ---------------- fused pool(relu(conv)), FIN=3, fp16 X/T ----------------
template<int N, int M, int FOUT>
__global__ void __launch_bounds__(256) pool_conv_f3_h(
    const half4* __restrict__ Xh, const half4* __restrict__ T,   // slices of N*32 cells
    const float* __restrict__ W, const float* __restrict__ bias,
    const int* __restrict__ pc, const float* __restrict__ pv,
    float* __restrict__ out)
{
  constexpr int F4 = FOUT / 4;
  constexpr size_t SL = (size_t)N * 32;        // cells per slice
  __shared__ float Ws[6 * 3 * FOUT];
  for (int i = threadIdx.x; i < 6 * 3 * FOUT; i += 256) Ws[i] = W[i];
  __syncthreads();
  const float4* Ws4 = (const float4*)Ws;
  int t = blockIdx.x * 256 + threadIdx.x;      // exact grid: M*32*F4
  int fo4 = t % F4;
  int b   = (t / F4) % BATCH;
  int m   = t / (F4 * BATCH);
  int c0 = pc[m * 3 + 0], c1 = pc[m * 3 + 1], c2 = pc[m * 3 + 2];
  float v0 = pv[m * 3 + 0], v1 = pv[m * 3 + 1], v2 = pv[m * 3 + 2];
  float4 bi = ((const float4*)bias)[fo4];
  float4 a0 = bi, a1 = bi, a2 = bi;
#pragma unroll
  for (int k = 0; k < 6; ++k) {
    const half4* base = (k == 0) ? Xh : (T + (size_t)(k - 1) * SL);
    float r0[4], r1[4], r2[4];
    h4f(base[(c0 << 5) | b], r0);
    h4f(base[(c1 << 5) | b], r1);
    h4f(base[(c2 << 5) | b], r2);
#pragma unroll
    for (int f = 0; f < 3; ++f) {
      float4 w = Ws4[(k * 3 + f) * F4 + fo4];
      fma4(a0, r0[f], w);
      fma4(a1, r1[f], w);
      fma4(a2, r2[f], w);
    }
  }
  a0 = relu4(a0); a1 = relu4(a1); a2 = relu4(a2);
  float4 acc;
  acc.x = v0*a0.x + v1*a1.x + v2*a2.x;
  acc.y = v0*a0.y + v1*a1.y + v2*a2.y;
  acc.z = v0*a0.z + v1*a1.z + v2*a2.z;
  acc.w = v0*a0.w + v1*a1.w + v2*a2.w;
  ((float4*)out)[((size_t)m * BATCH + b) * F4 + fo4] = acc;   // node-major fp32
}

// ---------------- LDS-resident Cheb recurrence (layers 1-3), fp16 T out ----------------
// R10's proven structure; LDS/registers fp32 (recurrence exact), only the
// global T store rounds to fp16 (half2, 4 B: half of R10's write bytes).
template<int N, int F, int THREADS, int MINW>
__global__ void __launch_bounds__(THREADS, MINW) cheb_recur_h(
    const float* __restrict__ X,    // node-major fp32 [N][32][F]
    const int* __restrict__ ec,     // [N][6]
    __half* __restrict__ Th)        // 5 slices, [n][32][F] halves
{
  constexpr int FS = 2;
  constexpr int NPT = N / THREADS;
  __shared__ float cur[N * FS];
  const float cI = -1.0f / 6.0f;
  const float cS = -1.0f / 3.0f;
  const int b = blockIdx.x & 31;
  const int fbase = (blockIdx.x >> 5) * FS;
  constexpr size_t SLH = (size_t)N * 32 * F;   // halves per slice
  float prevv[NPT][FS];
#pragma unroll
  for (int i = 0; i < NPT; ++i) {
    int n = threadIdx.x + i * THREADS;
    float2 v = *(const float2*)(X + ((size_t)n * 32 + b) * F + fbase);
    cur[n * FS + 0] = v.x;
    cur[n * FS + 1] = v.y;
  }
  __syncthreads();
#pragma unroll 1
  for (int k = 1; k <= 5; ++k) {
    float newv[NPT][FS];
    __half2* Tk2 = (__half2*)(Th + (size_t)(k - 1) * SLH);
#pragma unroll
    for (int i = 0; i < NPT; ++i) {
      int n = threadIdx.x + i * THREADS;
      const int* e = ec + n * 6;
      float s0 = 0.f, s1 = 0.f;
#pragma unroll
      for (int d = 0; d < 6; ++d) {
        int c = e[d];
        s0 += cur[c * FS + 0];
        s1 += cur[c * FS + 1];
      }
      float v0, v1;
      if (k == 1) { v0 = cI * s0; v1 = cI * s1; }
      else        { v0 = cS * s0 - prevv[i][0]; v1 = cS * s1 - prevv[i][1]; }
      newv[i][0] = v0; newv[i][1] = v1;
      Tk2[(((size_t)n * 32 + b) * F + fbase) >> 1] = __floats2half2_rn(v0, v1);
    }
    __syncthreads();
#pragma unroll
    for (int i = 0; i < NPT; ++i) {
      int n = threadIdx.x + i * THREADS;
      prevv[i][0] = cur[n * FS + 0];
      prevv[i][1] = cur[n * FS + 1];
      cur[n * FS + 0] = newv[i][0];
      cur[n * FS + 1] = newv[i][1];
    }
    __syncthreads();
  }
}

// ---------------- fused pool(relu(conv)), FIN=32, fp16 T ----------------
// Gathered T row = 32 halves = 64 B = exactly one cache line (was 2 fp32).
template<int N, int M, int FOUT, bool OUT_BM>
__global__ void __launch_bounds__(256) pool_conv_v32_h(
    const float* __restrict__ X, const __half* __restrict__ Th,
    const float* __restrict__ W, const float* __restrict__ bias,
    const int* __restrict__ pc, const float* __restrict__ pv,
    float* __restrict__ out)
{
  constexpr int FIN = 32;
  constexpr int F4 = FOUT / 4;
  constexpr size_t SLH = (size_t)N * 32 * FIN;   // halves per slice
  __shared__ float Ws[6 * FIN * FOUT];           // 24 KB or 48 KB
  for (int i = threadIdx.x; i < 6 * FIN * FOUT; i += 256) Ws[i] = W[i];
  __syncthreads();
  const float4* Ws4 = (const float4*)Ws;
  const float4* X4p = (const float4*)X;
  int t = blockIdx.x * 256 + threadIdx.x;        // exact grid: M*32*F4
  int fo4 = t % F4;
  int b   = (t / F4) % BATCH;
  int m   = t / (F4 * BATCH);
  int c0 = pc[m * 3 + 0], c1 = pc[m * 3 + 1], c2 = pc[m * 3 + 2];
  float v0 = pv[m * 3 + 0], v1 = pv[m * 3 + 1], v2 = pv[m * 3 + 2];
  float4 bi = ((const float4*)bias)[fo4];
  float4 a0 = bi, a1 = bi, a2 = bi;
  // k = 0 from fp32 X
  {
    const float4* r0 = X4p + ((size_t)c0 * BATCH + b) * 8;
    const float4* r1 = X4p + ((size_t)c1 * BATCH + b) * 8;
    const float4* r2 = X4p + ((size_t)c2 * BATCH + b) * 8;
#pragma unroll
    for (int fi = 0; fi < 8; ++fi) {
      float4 t0 = r0[fi], t1 = r1[fi], t2 = r2[fi];
#pragma unroll
      for (int ff = 0; ff < 4; ++ff) {
        float4 w = Ws4[(fi * 4 + ff) * F4 + fo4];
        fma4(a0, ((const float*)&t0)[ff], w);
        fma4(a1, ((const float*)&t1)[ff], w);
        fma4(a2, ((const float*)&t2)[ff], w);
      }
    }
  }
  // k = 1..5 from fp16 T
#pragma unroll 1
  for (int k = 1; k < 6; ++k) {
    const half4* base = (const half4*)(Th + (size_t)(k - 1) * SLH);
    const half4* r0 = base + ((size_t)c0 * 32 + b) * 8;
    const half4* r1 = base + ((size_t)c1 * 32 + b) * 8;
    const half4* r2 = base + ((size_t)c2 * 32 + b) * 8;
#pragma unroll
    for (int q = 0; q < 8; ++q) {
      float f0[4], f1[4], f2[4];
      h4f(r0[q], f0); h4f(r1[q], f1); h4f(r2[q], f2);
#pragma unroll
      for (int ff = 0; ff < 4; ++ff) {
        float4 w = Ws4[((k * 32) + q * 4 + ff) * F4 + fo4];
        fma4(a0, f0[ff], w);
        fma4(a1, f1[ff], w);
        fma4(a2, f2[ff], w);
      }
    }
  }
  a0 = relu4(a0); a1 = relu4(a1); a2 = relu4(a2);
  float4 acc;
  acc.x = v0*a0.x + v1*a1.x + v2*a2.x;
  acc.y = v0*a0.y + v1*a1.y + v2*a2.y;
  acc.z = v0*a0.z + v1*a1.z + v2*a2.z;
  acc.w = v0*a0.w + v1*a1.w + v2*a2.w;
  size_t oi = OUT_BM ? (((size_t)b * M + m) * F4 + fo4) : (((size_t)m * BATCH + b) * F4 + fo4);
  ((float4*)out)[oi] = acc;
}

// ---------------- encoder split-K partial ----------------
__global__ void __launch_bounds__(256) encoder_partial(
    const float* __restrict__ Xf, const float* __restrict__ encW,
    float* __restrict__ partial)
{
  int b  = blockIdx.x;        // 0..31
  int ks = blockIdx.y;        // 0..15
  int fo = threadIdx.x & 127;
  int half = threadIdx.x >> 7;
  const float* xr = Xf + b * 4096 + ks * 256 + half * 128;
  const float* w  = encW + (size_t)(ks * 256 + half * 128) * 128;
  float acc = 0.f;
#pragma unroll 8
  for (int i = 0; i < 128; ++i) acc += xr[i] * w[(size_t)i * 128 + fo];
  __shared__ float part[256];
  part[threadIdx.x] = acc;
  __syncthreads();
  if (half == 0) partial[(size_t)(b * 16 + ks) * 128 + fo] = part[fo] + part[128 + fo];
}

// ---------------- fused encoder-reduce + relu + classifier ----------------
__global__ void __launch_bounds__(128) encoder_reduce_cls(
    const float* __restrict__ partial, const float* __restrict__ encB,
    const float* __restrict__ clsW, const float* __restrict__ clsB,
    float* __restrict__ out)
{
  int b = blockIdx.x;           // 0..31
  int fo = threadIdx.x;         // 0..127
  float acc = encB[fo];
#pragma unroll
  for (int ks = 0; ks < 16; ++ks) acc += partial[(size_t)(b * 16 + ks) * 128 + fo];
  __shared__ float Hs[128];
  Hs[fo] = fmaxf(acc, 0.f);
  __syncthreads();
  if (fo < 10) {
    float s = clsB[fo];
#pragma unroll 4
    for (int f = 0; f < 128; ++f) s += Hs[f] * clsW[f * 10 + fo];
    out[b * 10 + fo] = s;
  }
}

extern "C" void kernel_launch(void* const* d_in, const int* in_sizes, int n_in,
                              void* d_out, int out_size, void* d_ws, size_t ws_size,
                              hipStream_t stream)
{
  const float* x   = (const float*)d_in[0];
  const int* ec0 = (const int*)d_in[2];
  const int* ec1 = (const int*)d_in[4];
  const int* ec2 = (const int*)d_in[6];
  const int* ec3 = (const int*)d_in[8];
  const int* pc0 = (const int*)d_in[10]; const float* pv0 = (const float*)d_in[11];
  const int* pc1 = (const int*)d_in[13]; const float* pv1 = (const float*)d_in[14];
  const int* pc2 = (const int*)d_in[16]; const float* pv2 = (const float*)d_in[17];
  const int* pc3 = (const int*)d_in[19]; const float* pv3 = (const float*)d_in[20];
  const float* W0 = (const float*)d_in[21]; const float* b0 = (const float*)d_in[22];
  const float* W1 = (const float*)d_in[23]; const float* b1 = (const float*)d_in[24];
  const float* W2 = (const float*)d_in[25]; const float* b2 = (const float*)d_in[26];
  const float* W3 = (const float*)d_in[27]; const float* b3 = (const float*)d_in[28];
  const float* encW = (const float*)d_in[29]; const float* encB = (const float*)d_in[30];
  const float* clsW = (const float*)d_in[31]; const float* clsB = (const float*)d_in[32];
  float* out = (float*)d_out;

  float* ws = (float*)d_ws;
  half4*  Xh = (half4*)ws;               // 524,288 cells (1,048,576 floats)
  __half* Th = (__half*)(ws + 1048576);  // 20,971,520 halves (10,485,760 floats)
  float* X1 = ws + 1048576 + 10485760;   // 4,194,304
  float* X2 = X1 + 4194304;              // 1,048,576
  float* X3 = X2 + 1048576;              // 262,144
  float* X4 = X3 + 262144;               // 131,072  ([32][4096])
  float* P  = X4 + 131072;               // 65,536

  const float cI = -1.0f / 6.0f;
  const float cS = -1.0f / 3.0f;
  dim3 blk(256);

  transpose_h<<<dim3(2048), blk, 0, stream>>>(x, Xh);

  // ================= layer 0: N=16384, M=4096, fp16 chain =================
  // Slice = 16384*32 cells * 8 B = 4 MB -> fits one XCD L2; gathers L2-hit.
  {
    constexpr size_t S = (size_t)16384 * 32;   // cells per slice
    half4* T4 = (half4*)Th;
    cheb_step_h<16384><<<dim3(2048), blk, 0, stream>>>(Xh,       Xh,       ec0, T4,        cI,  0.f);
    cheb_step_h<16384><<<dim3(2048), blk, 0, stream>>>(T4,       Xh,       ec0, T4 + S,    cS, -1.f);
    cheb_step_h<16384><<<dim3(2048), blk, 0, stream>>>(T4 + S,   T4,       ec0, T4 + 2*S,  cS, -1.f);
    cheb_step_h<16384><<<dim3(2048), blk, 0, stream>>>(T4 + 2*S, T4 + S,   ec0, T4 + 3*S,  cS, -1.f);
    cheb_step_h<16384><<<dim3(2048), blk, 0, stream>>>(T4 + 3*S, T4 + 2*S, ec0, T4 + 4*S,  cS, -1.f);
    pool_conv_f3_h<16384, 4096, 32><<<dim3(4096), blk, 0, stream>>>(
        Xh, (const half4*)Th, W0, b0, pc0, pv0, X1);
  }
  // ================= layer 1: N=4096, F=32, M=1024 =================
  {
    cheb_recur_h<4096, 32, 512, 4><<<dim3(512), dim3(512), 0, stream>>>(X1, ec1, Th);
    pool_conv_v32_h<4096, 1024, 32, false><<<dim3(1024), blk, 0, stream>>>(
        X1, Th, W1, b1, pc1, pv1, X2);
  }
  // ================= layer 2: N=1024, F=32, M=256 =================
  {
    cheb_recur_h<1024, 32, 256, 4><<<dim3(512), blk, 0, stream>>>(X2, ec2, Th);
    pool_conv_v32_h<1024, 256, 32, false><<<dim3(256), blk, 0, stream>>>(
        X2, Th, W2, b2, pc2, pv2, X3);
  }
  // ================= layer 3: N=256, F=32, M=64, FOUT=64, batch-major out =================
  {
    cheb_recur_h<256, 32, 256, 4><<<dim3(512), blk, 0, stream>>>(X3, ec3, Th);
    pool_conv_v32_h<256, 64, 64, true><<<dim3(128), blk, 0, stream>>>(
        X3, Th, W3, b3, pc3, pv3, X4);
  }
  // ================= head =================
  encoder_partial<<<dim3(32, 16), blk, 0, stream>>>(X4, encW, P);
  encoder_reduce_cls<<<dim3(32), dim3(128), 0, stream>>>(P, encB, clsW, clsB, out);
}

// Round 15
// 281.772 us; speedup vs baseline: 1.4975x; 1.1328x over previous
//
#include <hip/hip_runtime.h>
#include <hip/hip_fp16.h>
#include <cstddef>
#include <cstdint>

#define BATCH 32

// T and the transposed input are stored FP16 (compute fp32). Layouts:
//   Xh : [16384][32][4] halves (pad=0)        = 1,048,576 floats region
//   Th : T1..T5; layer0 slices [n][32][4]h, layers1-3 [n][32][32]h
//        region = 10,485,760 floats (20,971,520 halves)
//   X1 : 4,194,304 fp32   X2 : 1,048,576   X3 : 262,144
//   X4 : 131,072 ([32][4096] fp32, batch-major)   P : 65,536

struct alignas(8) half4 { __half2 lo, hi; };

__device__ __forceinline__ void h4f(const half4 h, float f[4]) {
  float2 a = __half22float2(h.lo);
  float2 c = __half22float2(h.hi);
  f[0] = a.x; f[1] = a.y; f[2] = c.x; f[3] = c.y;
}
__device__ __forceinline__ void fma4(float4& a, float s, const float4& w) {
  a.x += s * w.x; a.y += s * w.y; a.z += s * w.z; a.w += s * w.w;
}
__device__ __forceinline__ float4 relu4(const float4& a) {
  return make_float4(fmaxf(a.x, 0.f), fmaxf(a.y, 0.f), fmaxf(a.z, 0.f), fmaxf(a.w, 0.f));
}

// ---------------- transpose x[b][n][3] -> Xh[n][32][4] fp16 (pad=0) ----------------
__global__ void __launch_bounds__(256) transpose_h(
    const float* __restrict__ x, half4* __restrict__ xh)
{
  int t = blockIdx.x * 256 + threadIdx.x;   // n*32 + b
  int n = t >> 5;
  int b = t & 31;
  const float* src = x + ((size_t)b * 16384 + n) * 3;
  half4 h;
  h.lo = __floats2half2_rn(src[0], src[1]);
  h.hi = __floats2half2_rn(src[2], 0.f);
  xh[t] = h;
}

// ---------------- fp16 Cheb step, layer 0 ----------------
// One thread per (n,b) cell. Slice = 4 MB -> fits one XCD's L2; gathers hit L2.
template<int N>
__global__ void __launch_bounds__(256) cheb_step_h(
    const half4* __restrict__ Tin, const half4* __restrict__ Tpp,
    const int* __restrict__ ec, half4* __restrict__ Tout,
    float coef, float beta)
{
  int idx = blockIdx.x * 256 + threadIdx.x;   // n*32 + b, exact grid
  int n = idx >> 5;
  int b = idx & 31;
  const int* e = ec + n * 6;
  float s0 = 0.f, s1 = 0.f, s2 = 0.f;
#pragma unroll
  for (int d = 0; d < 6; ++d) {
    half4 v = Tin[(e[d] << 5) | b];
    float2 a = __half22float2(v.lo);
    float2 c = __half22float2(v.hi);
    s0 += a.x; s1 += a.y; s2 += c.x;
  }
  half4 p = Tpp[idx];
  float2 pa = __half22float2(p.lo);
  float2 pc = __half22float2(p.hi);
  half4 o;
  o.lo = __floats2half2_rn(coef * s0 + beta * pa.x, coef * s1 + beta * pa.y);
  o.hi = __floats2half2_rn(coef * s2 + beta * pc.x, 0.f);
  Tout[idx] = o;
}

// ---------------- fused pool(relu(conv)), FIN=3, fp16 X/T ----------------
template<int N, int M, int FOUT>
__global__ void __launch_bounds__(256) pool_conv_f3_h(
    const half4* __restrict__ Xh, const half4* __restrict__ T,   // slices of N*32 cells
    const float* __restrict__ W, const float* __restrict__ bias,
    const int* __restrict__ pc, const float* __restrict__ pv,
    float* __restrict__ out)
{
  constexpr int F4 = FOUT / 4;
  constexpr size_t SL = (size_t)N * 32;        // cells per slice
  __shared__ float Ws[6 * 3 * FOUT];
  for (int i = threadIdx.x; i < 6 * 3 * FOUT; i += 256) Ws[i] = W[i];
  __syncthreads();
  const float4* Ws4 = (const float4*)Ws;
  int t = blockIdx.x * 256 + threadIdx.x;      // exact grid: M*32*F4
  int fo4 = t % F4;
  int b   = (t / F4) % BATCH;
  int m   = t / (F4 * BATCH);
  int c0 = pc[m * 3 + 0], c1 = pc[m * 3 + 1], c2 = pc[m * 3 + 2];
  float v0 = pv[m * 3 + 0], v1 = pv[m * 3 + 1], v2 = pv[m * 3 + 2];
  float4 bi = ((const float4*)bias)[fo4];
  float4 a0 = bi, a1 = bi, a2 = bi;
#pragma unroll
  for (int k = 0; k < 6; ++k) {
    const half4* base = (k == 0) ? Xh : (T + (size_t)(k - 1) * SL);
    float r0[4], r1[4], r2[4];
    h4f(base[(c0 << 5) | b], r0);
    h4f(base[(c1 << 5) | b], r1);
    h4f(base[(c2 << 5) | b], r2);
#pragma unroll
    for (int f = 0; f < 3; ++f) {
      float4 w = Ws4[(k * 3 + f) * F4 + fo4];
      fma4(a0, r0[f], w);
      fma4(a1, r1[f], w);
      fma4(a2, r2[f], w);
    }
  }
  a0 = relu4(a0); a1 = relu4(a1); a2 = relu4(a2);
  float4 acc;
  acc.x = v0*a0.x + v1*a1.x + v2*a2.x;
  acc.y = v0*a0.y + v1*a1.y + v2*a2.y;
  acc.z = v0*a0.z + v1*a1.z + v2*a2.z;
  acc.w = v0*a0.w + v1*a1.w + v2*a2.w;
  ((float4*)out)[((size_t)m * BATCH + b) * F4 + fo4] = acc;   // node-major fp32
}

// ---------------- LDS-resident Cheb recurrence v6 (layers 1-3): FS=4, b128 gathers ----------------
// Block = (b, f-slab of 4). LDS holds T_{k-1} as float4[N] -> one ds_read_b128
// per edge (was 2x ds_read_b32: 4x fewer LDS instructions, R14's measured
// limiter). prevv/newv = 2*NPT*4 floats; NPT<=4 keeps the R10-proven register
// footprint (no scratch). Global T store = half4 (8 B) per owned node/step.
template<int N, int F, int THREADS, int MINW>
__global__ void __launch_bounds__(THREADS, MINW) cheb_recur_h4(
    const float* __restrict__ X,    // node-major fp32 [N][32][F]
    const int* __restrict__ ec,     // [N][6]
    __half* __restrict__ Th)        // 5 slices, [n][32][F] halves
{
  constexpr int NPT = N / THREADS;
  __shared__ float4 cur[N];                    // 16 B per node
  const float cI = -1.0f / 6.0f;
  const float cS = -1.0f / 3.0f;
  const int b = blockIdx.x & 31;
  const int fbase = (blockIdx.x >> 5) * 4;     // slab of 4 features
  constexpr size_t SLH = (size_t)N * 32 * F;   // halves per slice
  float4 prevv[NPT];
  // load T0 slab (float4)
#pragma unroll
  for (int i = 0; i < NPT; ++i) {
    int n = threadIdx.x + i * THREADS;
    cur[n] = *(const float4*)(X + ((size_t)n * 32 + b) * F + fbase);
  }
  __syncthreads();
#pragma unroll 1
  for (int k = 1; k <= 5; ++k) {
    float4 newv[NPT];
    __half* Tk = Th + (size_t)(k - 1) * SLH;
#pragma unroll
    for (int i = 0; i < NPT; ++i) {
      int n = threadIdx.x + i * THREADS;
      const int* e = ec + n * 6;
      float4 s = make_float4(0.f, 0.f, 0.f, 0.f);
#pragma unroll
      for (int d = 0; d < 6; ++d) {
        float4 t = cur[e[d]];                  // ds_read_b128
        s.x += t.x; s.y += t.y; s.z += t.z; s.w += t.w;
      }
      float4 v;
      if (k == 1) {
        v.x = cI * s.x; v.y = cI * s.y; v.z = cI * s.z; v.w = cI * s.w;
      } else {
        v.x = cS * s.x - prevv[i].x; v.y = cS * s.y - prevv[i].y;
        v.z = cS * s.z - prevv[i].z; v.w = cS * s.w - prevv[i].w;
      }
      newv[i] = v;
      half4 h;
      h.lo = __floats2half2_rn(v.x, v.y);
      h.hi = __floats2half2_rn(v.z, v.w);
      *(half4*)(Tk + ((size_t)n * 32 + b) * F + fbase) = h;
    }
    __syncthreads();   // all gathers of T_{k-1} complete
#pragma unroll
    for (int i = 0; i < NPT; ++i) {
      int n = threadIdx.x + i * THREADS;
      prevv[i] = cur[n];                       // own slot still = T_{k-1}
      cur[n] = newv[i];                        // T_k -> cur
    }
    __syncthreads();
  }
}

// ---------------- fused pool(relu(conv)), FIN=32, fp16 T ----------------
// Gathered T row = 32 halves = 64 B = exactly one cache line.
template<int N, int M, int FOUT, bool OUT_BM>
__global__ void __launch_bounds__(256) pool_conv_v32_h(
    const float* __restrict__ X, const __half* __restrict__ Th,
    const float* __restrict__ W, const float* __restrict__ bias,
    const int* __restrict__ pc, const float* __restrict__ pv,
    float* __restrict__ out)
{
  constexpr int FIN = 32;
  constexpr int F4 = FOUT / 4;
  constexpr size_t SLH = (size_t)N * 32 * FIN;   // halves per slice
  __shared__ float Ws[6 * FIN * FOUT];           // 24 KB or 48 KB
  for (int i = threadIdx.x; i < 6 * FIN * FOUT; i += 256) Ws[i] = W[i];
  __syncthreads();
  const float4* Ws4 = (const float4*)Ws;
  const float4* X4p = (const float4*)X;
  int t = blockIdx.x * 256 + threadIdx.x;        // exact grid: M*32*F4
  int fo4 = t % F4;
  int b   = (t / F4) % BATCH;
  int m   = t / (F4 * BATCH);
  int c0 = pc[m * 3 + 0], c1 = pc[m * 3 + 1], c2 = pc[m * 3 + 2];
  float v0 = pv[m * 3 + 0], v1 = pv[m * 3 + 1], v2 = pv[m * 3 + 2];
  float4 bi = ((const float4*)bias)[fo4];
  float4 a0 = bi, a1 = bi, a2 = bi;
  // k = 0 from fp32 X
  {
    const float4* r0 = X4p + ((size_t)c0 * BATCH + b) * 8;
    const float4* r1 = X4p + ((size_t)c1 * BATCH + b) * 8;
    const float4* r2 = X4p + ((size_t)c2 * BATCH + b) * 8;
#pragma unroll
    for (int fi = 0; fi < 8; ++fi) {
      float4 t0 = r0[fi], t1 = r1[fi], t2 = r2[fi];
#pragma unroll
      for (int ff = 0; ff < 4; ++ff) {
        float4 w = Ws4[(fi * 4 + ff) * F4 + fo4];
        fma4(a0, ((const float*)&t0)[ff], w);
        fma4(a1, ((const float*)&t1)[ff], w);
        fma4(a2, ((const float*)&t2)[ff], w);
      }
    }
  }
  // k = 1..5 from fp16 T
#pragma unroll 1
  for (int k = 1; k < 6; ++k) {
    const half4* base = (const half4*)(Th + (size_t)(k - 1) * SLH);
    const half4* r0 = base + ((size_t)c0 * 32 + b) * 8;
    const half4* r1 = base + ((size_t)c1 * 32 + b) * 8;
    const half4* r2 = base + ((size_t)c2 * 32 + b) * 8;
#pragma unroll
    for (int q = 0; q < 8; ++q) {
      float f0[4], f1[4], f2[4];
      h4f(r0[q], f0); h4f(r1[q], f1); h4f(r2[q], f2);
#pragma unroll
      for (int ff = 0; ff < 4; ++ff) {
        float4 w = Ws4[((k * 32) + q * 4 + ff) * F4 + fo4];
        fma4(a0, f0[ff], w);
        fma4(a1, f1[ff], w);
        fma4(a2, f2[ff], w);
      }
    }
  }
  a0 = relu4(a0); a1 = relu4(a1); a2 = relu4(a2);
  float4 acc;
  acc.x = v0*a0.x + v1*a1.x + v2*a2.x;
  acc.y = v0*a0.y + v1*a1.y + v2*a2.y;
  acc.z = v0*a0.z + v1*a1.z + v2*a2.z;
  acc.w = v0*a0.w + v1*a1.w + v2*a2.w;
  size_t oi = OUT_BM ? (((size_t)b * M + m) * F4 + fo4) : (((size_t)m * BATCH + b) * F4 + fo4);
  ((float4*)out)[oi] = acc;
}

// ---------------- encoder split-K partial ----------------
__global__ void __launch_bounds__(256) encoder_partial(
    const float* __restrict__ Xf, const float* __restrict__ encW,
    float* __restrict__ partial)
{
  int b  = blockIdx.x;        // 0..31
  int ks = blockIdx.y;        // 0..15
  int fo = threadIdx.x & 127;
  int half = threadIdx.x >> 7;
  const float* xr = Xf + b * 4096 + ks * 256 + half * 128;
  const float* w  = encW + (size_t)(ks * 256 + half * 128) * 128;
  float acc = 0.f;
#pragma unroll 8
  for (int i = 0; i < 128; ++i) acc += xr[i] * w[(size_t)i * 128 + fo];
  __shared__ float part[256];
  part[threadIdx.x] = acc;
  __syncthreads();
  if (half == 0) partial[(size_t)(b * 16 + ks) * 128 + fo] = part[fo] + part[128 + fo];
}

// ---------------- fused encoder-reduce + relu + classifier ----------------
__global__ void __launch_bounds__(128) encoder_reduce_cls(
    const float* __restrict__ partial, const float* __restrict__ encB,
    const float* __restrict__ clsW, const float* __restrict__ clsB,
    float* __restrict__ out)
{
  int b = blockIdx.x;           // 0..31
  int fo = threadIdx.x;         // 0..127
  float acc = encB[fo];
#pragma unroll
  for (int ks = 0; ks < 16; ++ks) acc += partial[(size_t)(b * 16 + ks) * 128 + fo];
  __shared__ float Hs[128];
  Hs[fo] = fmaxf(acc, 0.f);
  __syncthreads();
  if (fo < 10) {
    float s = clsB[fo];
#pragma unroll 4
    for (int f = 0; f < 128; ++f) s += Hs[f] * clsW[f * 10 + fo];
    out[b * 10 + fo] = s;
  }
}

extern "C" void kernel_launch(void* const* d_in, const int* in_sizes, int n_in,
                              void* d_out, int out_size, void* d_ws, size_t ws_size,
                              hipStream_t stream)
{
  const float* x   = (const float*)d_in[0];
  const int* ec0 = (const int*)d_in[2];
  const int* ec1 = (const int*)d_in[4];
  const int* ec2 = (const int*)d_in[6];
  const int* ec3 = (const int*)d_in[8];
  const int* pc0 = (const int*)d_in[10]; const float* pv0 = (const float*)d_in[11];
  const int* pc1 = (const int*)d_in[13]; const float* pv1 = (const float*)d_in[14];
  const int* pc2 = (const int*)d_in[16]; const float* pv2 = (const float*)d_in[17];
  const int* pc3 = (const int*)d_in[19]; const float* pv3 = (const float*)d_in[20];
  const float* W0 = (const float*)d_in[21]; const float* b0 = (const float*)d_in[22];
  const float* W1 = (const float*)d_in[23]; const float* b1 = (const float*)d_in[24];
  const float* W2 = (const float*)d_in[25]; const float* b2 = (const float*)d_in[26];
  const float* W3 = (const float*)d_in[27]; const float* b3 = (const float*)d_in[28];
  const float* encW = (const float*)d_in[29]; const float* encB = (const float*)d_in[30];
  const float* clsW = (const float*)d_in[31]; const float* clsB = (const float*)d_in[32];
  float* out = (float*)d_out;

  float* ws = (float*)d_ws;
  half4*  Xh = (half4*)ws;               // 524,288 cells (1,048,576 floats)
  __half* Th = (__half*)(ws + 1048576);  // 20,971,520 halves (10,485,760 floats)
  float* X1 = ws + 1048576 + 10485760;   // 4,194,304
  float* X2 = X1 + 4194304;              // 1,048,576
  float* X3 = X2 + 1048576;              // 262,144
  float* X4 = X3 + 262144;               // 131,072  ([32][4096])
  float* P  = X4 + 131072;               // 65,536

  const float cI = -1.0f / 6.0f;
  const float cS = -1.0f / 3.0f;
  dim3 blk(256);

  transpose_h<<<dim3(2048), blk, 0, stream>>>(x, Xh);

  // ================= layer 0: N=16384, M=4096, fp16 chain =================
  // Slice = 16384*32 cells * 8 B = 4 MB -> fits one XCD L2; gathers L2-hit.
  {
    constexpr size_t S = (size_t)16384 * 32;   // cells per slice
    half4* T4 = (half4*)Th;
    cheb_step_h<16384><<<dim3(2048), blk, 0, stream>>>(Xh,       Xh,       ec0, T4,        cI,  0.f);
    cheb_step_h<16384><<<dim3(2048), blk, 0, stream>>>(T4,       Xh,       ec0, T4 + S,    cS, -1.f);
    cheb_step_h<16384><<<dim3(2048), blk, 0, stream>>>(T4 + S,   T4,       ec0, T4 + 2*S,  cS, -1.f);
    cheb_step_h<16384><<<dim3(2048), blk, 0, stream>>>(T4 + 2*S, T4 + S,   ec0, T4 + 3*S,  cS, -1.f);
    cheb_step_h<16384><<<dim3(2048), blk, 0, stream>>>(T4 + 3*S, T4 + 2*S, ec0, T4 + 4*S,  cS, -1.f);
    pool_conv_f3_h<16384, 4096, 32><<<dim3(4096), blk, 0, stream>>>(
        Xh, (const half4*)Th, W0, b0, pc0, pv0, X1);
  }
  // ================= layer 1: N=4096, F=32, M=1024 =================
  // FS=4: 256 blocks (32 b x 8 slabs) x 1024 thr (NPT=4), 64 KB LDS,
  // one ds_read_b128 per edge.
  {
    cheb_recur_h4<4096, 32, 1024, 4><<<dim3(256), dim3(1024), 0, stream>>>(X1, ec1, Th);
    pool_conv_v32_h<4096, 1024, 32, false><<<dim3(1024), blk, 0, stream>>>(
        X1, Th, W1, b1, pc1, pv1, X2);
  }
  // ================= layer 2: N=1024, F=32, M=256 =================
  {
    cheb_recur_h4<1024, 32, 256, 4><<<dim3(256), blk, 0, stream>>>(X2, ec2, Th);
    pool_conv_v32_h<1024, 256, 32, false><<<dim3(256), blk, 0, stream>>>(
        X2, Th, W2, b2, pc2, pv2, X3);
  }
  // ================= layer 3: N=256, F=32, M=64, FOUT=64, batch-major out =================
  {
    cheb_recur_h4<256, 32, 256, 4><<<dim3(256), blk, 0, stream>>>(X3, ec3, Th);
    pool_conv_v32_h<256, 64, 64, true><<<dim3(128), blk, 0, stream>>>(
        X3, Th, W3, b3, pc3, pv3, X4);
  }
  // ================= head =================
  encoder_partial<<<dim3(32, 16), blk, 0, stream>>>(X4, encW, P);
  encoder_reduce_cls<<<dim3(32), dim3(128), 0, stream>>>(P, encB, clsW, clsB, out);
}